// Round 2
// baseline (555.195 us; speedup 1.0000x reference)
//
#include <hip/hip_runtime.h>

// MLPPredictor: score[e,c] = bias[c] + sum_k concat(h[src[e]], h[dst[e]])[k] * W[c][k]
// N_NODES=100000, E=6.4M, D=5, C=16. fp32 in/out, int32 indices.
//
// v3 theory: v2's dur (549us) ~= 256us harness workspace re-poison fill (1.6GB
// @6.3TB/s, visible as fillBufferAligned in rocprof) + ~290us of kernels.
// Using d_ws triggers a timed re-poison => drop the workspace entirely.
//  * Gather from RAW h (20B rows, no padded copy): quad lane j, row r = (j>=2 ? dst : src):
//      even lane: dwordx4 at h+5r   -> elems 0..3
//      odd  lane: dwordx4 at h+5r+1 -> elems 1..4   (always in-bounds; last read = elem 499999)
//    2 quad_perm DPPs (xor1) recover elem4/elem0; 5 DPPs (xor2) swap u<->v.
//    ~2.5 cache lines/edge (vs 2.0 padded) but zero workspace use.
//  * Depth-2 software pipeline: issue pair(i+1) gathers BEFORE consuming pair(i);
//    indices prefetched two pairs ahead (clamped, always safe). Gather latency
//    (~300-600cy L2/L3) hides under one full iteration of FMA+DPP+store.
//  * Non-temporal idx loads + out stores: keep the 460MB stream from evicting
//    the 2MB h table out of L2.
// Output mapping unchanged: thread g -> edge g>>2, class-quad g&3, one float4
// NT store at out + g*4 (fully coalesced, 1KB/wave).

typedef float f4v __attribute__((ext_vector_type(4)));
typedef f4v uf4v __attribute__((aligned(4)));   // 4B-aligned vector load (dwordx4 needs dword align only)

constexpr int C = 16;
constexpr int TWO_D = 10;

// quad_perm DPP: xor1 = perm[1,0,3,2] = 0xB1 ; xor2 = perm[2,3,0,1] = 0x4E
template <int CTRL>
__device__ __forceinline__ float qperm(float x) {
    return __int_as_float(
        __builtin_amdgcn_mov_dpp(__float_as_int(x), CTRL, 0xF, 0xF, true));
}

__global__ __launch_bounds__(256) void edge_mlp_v3(
    const float* __restrict__ h,    // [N_NODES][5] raw rows
    const int* __restrict__ src,
    const int* __restrict__ dst,
    const float* __restrict__ Ww,   // [C][2D]
    const float* __restrict__ Wb,   // [C]
    float* __restrict__ out,        // [E][C]
    int totalItems)                 // E*4
{
    __shared__ float sW[C * TWO_D + C];
    for (int i = threadIdx.x; i < C * TWO_D + C; i += blockDim.x)
        sW[i] = (i < C * TWO_D) ? Ww[i] : Wb[i - C * TWO_D];
    __syncthreads();

    const int tid0 = blockIdx.x * blockDim.x + threadIdx.x;
    const int q = tid0 & 3;            // invariant: stride % 4 == 0
    const bool odd = (q & 1) != 0;     // loads elems 1..4 of its row
    const bool isV = (q >= 2);         // loads the dst row

    // register-resident W tile for my 4 classes
    float w[4][TWO_D], bias[4];
#pragma unroll
    for (int j = 0; j < 4; ++j) {
        const int c = q * 4 + j;
#pragma unroll
        for (int k = 0; k < TWO_D; ++k) w[j][k] = sW[c * TWO_D + k];
        bias[j] = sW[C * TWO_D + c];
    }

    const int stride = gridDim.x * blockDim.x;
    const int stride2 = stride * 2;
    const int TImax = totalItems - 1;

    auto clampE = [&](int g) { return (g < TImax ? g : TImax) >> 2; };

    // one dwordx4 gather for my quad role, rows (s,d) of this item
    auto loadrow = [&](int s, int d) -> f4v {
        const int r = isV ? d : s;
        const float* p = h + (size_t)r * 5 + (odd ? 1 : 0);
        return *reinterpret_cast<const uf4v*>(p);
    };

    // assemble u0..u4 / v0..v4 from my f4v + quad exchanges, compute, store
    auto body = [&](const f4v m, int gout, bool doStore) {
        // xor1: partner half-row; we only need its elem[0] (for odd) / elem[3] (for even)
        const float o0 = qperm<0xB1>(m[0]);
        const float o3 = qperm<0xB1>(m[3]);
        // my row elems 0..4
        const float a0 = odd ? o0   : m[0];
        const float a1 = odd ? m[0] : m[1];
        const float a2 = odd ? m[1] : m[2];
        const float a3 = odd ? m[2] : m[3];
        const float a4 = odd ? m[3] : o3;
        // xor2: the other node's row
        const float b0 = qperm<0x4E>(a0);
        const float b1 = qperm<0x4E>(a1);
        const float b2 = qperm<0x4E>(a2);
        const float b3 = qperm<0x4E>(a3);
        const float b4 = qperm<0x4E>(a4);

        const float u0 = isV ? b0 : a0, v0 = isV ? a0 : b0;
        const float u1 = isV ? b1 : a1, v1 = isV ? a1 : b1;
        const float u2 = isV ? b2 : a2, v2 = isV ? a2 : b2;
        const float u3 = isV ? b3 : a3, v3 = isV ? a3 : b3;
        const float u4 = isV ? b4 : a4, v4 = isV ? a4 : b4;

        f4v r;
#pragma unroll
        for (int j = 0; j < 4; ++j) {
            float a = bias[j];
            a += u0 * w[j][0] + u1 * w[j][1] + u2 * w[j][2] + u3 * w[j][3] + u4 * w[j][4];
            a += v0 * w[j][5] + v1 * w[j][6] + v2 * w[j][7] + v3 * w[j][8] + v4 * w[j][9];
            r[j] = a;
        }
        if (doStore)
            __builtin_nontemporal_store(r, reinterpret_cast<f4v*>(out + (size_t)gout * 4));
    };

    // ---- software pipeline ----
    // P0 indices
    int eA = clampE(tid0), eB = clampE(tid0 + stride);
    int sA = __builtin_nontemporal_load(src + eA);
    int dA = __builtin_nontemporal_load(dst + eA);
    int sB = __builtin_nontemporal_load(src + eB);
    int dB = __builtin_nontemporal_load(dst + eB);
    // P0 gathers in flight
    f4v gA = loadrow(sA, dA);
    f4v gB = loadrow(sB, dB);
    // P1 indices
    {
        const int gn = tid0 + stride2;
        eA = clampE(gn); eB = clampE(gn + stride);
        sA = __builtin_nontemporal_load(src + eA);
        dA = __builtin_nontemporal_load(dst + eA);
        sB = __builtin_nontemporal_load(src + eB);
        dB = __builtin_nontemporal_load(dst + eB);
    }

    for (int g = tid0; g < totalItems; g += stride2) {
        // issue pair(i+1) gathers (indices ready from last iter)
        const f4v nA = loadrow(sA, dA);
        const f4v nB = loadrow(sB, dB);
        // prefetch pair(i+2) indices (clamped -> always safe, no divergence)
        const int gn = g + 2 * stride2;
        eA = clampE(gn); eB = clampE(gn + stride);
        sA = __builtin_nontemporal_load(src + eA);
        dA = __builtin_nontemporal_load(dst + eA);
        sB = __builtin_nontemporal_load(src + eB);
        dB = __builtin_nontemporal_load(dst + eB);
        // consume pair(i) while pair(i+1) is in flight
        body(gA, g, true);
        body(gB, g + stride, (g + stride) < totalItems);
        gA = nA; gB = nB;
    }
}

extern "C" void kernel_launch(void* const* d_in, const int* in_sizes, int n_in,
                              void* d_out, int out_size, void* d_ws, size_t ws_size,
                              hipStream_t stream) {
    const float* h   = (const float*)d_in[0];   // [100000, 5]
    const int*   src = (const int*)d_in[1];     // [E]
    const int*   dst = (const int*)d_in[2];     // [E]
    const float* Ww  = (const float*)d_in[3];   // [16, 10]
    const float* Wb  = (const float*)d_in[4];   // [16]
    float* out = (float*)d_out;                 // [E, 16]

    const int E = in_sizes[1];
    const int totalItems = E * 4;               // 25.6M, fits int

    // NOTE: d_ws deliberately untouched — using it appears to trigger a timed
    // 1.6GB workspace re-poison fill (~256us) in the harness.
    edge_mlp_v3<<<4096, 256, 0, stream>>>(h, src, dst, Ww, Wb, out, totalItems);
}